// Round 2
// baseline (218.687 us; speedup 1.0000x reference)
//
#include <hip/hip_runtime.h>

// QFD loss: out = 0.1 * sum_b diff_b^T A diff_b, A_ij = 1 - |i-j|/85.
// Identity per row: with L_k = prefix sums of d=|in-tgt|,
//   S = L_84, a1 = sum_{k<=84} L_k, b2 = sum_{k<=84} L_k^2,
//   sumL = a1 - S, sumL2 = b2 - S^2,
//   q = S^2 - (2/85) * (S*sumL - sumL2).
//
// R7: six structural variants (reg-staged x4, single-shot DMA, dbuf
// persistent DMA) all pinned at 65-72 us = 2.5 TB/s. L3-warm dispatches run
// the SAME time as HBM-fed -> stall is downstream of L3. Per-CU DMA rate =
// one 1KB global_load_lds per ~245 cy (= L2-miss turnaround); m97 sustains
// 13 TB/s DMA but on L2-resident panels. Theory: LDS-DMA return path
// serializes on L2 misses; our 178 MB working set misses L2 always.
// Fix: drop LDS staging entirely. One thread = one row; 21 f4 + 1 scalar
// loads per array into a statically-unrolled 3-stage register ring
// (distance-2 prefetch, ~12-18 vmcnt-counted loads in flight per wave),
// sequential in-thread scan, no barriers, no LDS data path.
// 1024 blocks = 4 blocks/CU x 4 waves = 16 waves/CU.

#define QFD_D 85
#define THREADS 256
#define NWAVES (THREADS / 64)

// Rows are 340 B apart -> only 4-byte aligned. gfx950 supports unaligned
// global access; align(4) vector type lets LLVM emit global_load_dwordx4.
typedef float f4a __attribute__((ext_vector_type(4), aligned(4)));

__global__ __launch_bounds__(THREADS, 4) void qfd_kernel(
    const float* __restrict__ in, const float* __restrict__ tgt,
    float* __restrict__ partial, int B) {
    __shared__ float wsum[NWAVES];
    const int tid  = threadIdx.x;
    const int lane = tid & 63;
    const int wave = tid >> 6;
    const int row  = blockIdx.x * THREADS + tid;

    float qrow = 0.0f;
    if (row < B) {
        const float* pi = in  + (size_t)row * QFD_D;
        const float* pt = tgt + (size_t)row * QFD_D;

        float l = 0.0f, a1 = 0.0f, b2 = 0.0f;

        // Group g = floats [12g, 12g+12). 7 groups = 84 floats + elem 84.
#define LOADG(SI0,SI1,SI2,ST0,ST1,ST2,g)          \
        SI0 = *(const f4a*)(pi + 12*(g));         \
        SI1 = *(const f4a*)(pi + 12*(g) + 4);     \
        SI2 = *(const f4a*)(pi + 12*(g) + 8);     \
        ST0 = *(const f4a*)(pt + 12*(g));         \
        ST1 = *(const f4a*)(pt + 12*(g) + 4);     \
        ST2 = *(const f4a*)(pt + 12*(g) + 8);

#define C1(vi,vt) { float v = fabsf((vi) - (vt)); l += v; a1 += l; b2 = fmaf(l, l, b2); }
#define CONSG(SI0,SI1,SI2,ST0,ST1,ST2)                                    \
        C1(SI0.x,ST0.x) C1(SI0.y,ST0.y) C1(SI0.z,ST0.z) C1(SI0.w,ST0.w)   \
        C1(SI1.x,ST1.x) C1(SI1.y,ST1.y) C1(SI1.z,ST1.z) C1(SI1.w,ST1.w)   \
        C1(SI2.x,ST2.x) C1(SI2.y,ST2.y) C1(SI2.z,ST2.z) C1(SI2.w,ST2.w)

        // 3-stage register ring: 18 f4 = 72 VGPR of data; all indices static.
        f4a Ai0,Ai1,Ai2, At0,At1,At2;
        f4a Bi0,Bi1,Bi2, Bt0,Bt1,Bt2;
        f4a Ci0,Ci1,Ci2, Ct0,Ct1,Ct2;

        float e84i = pi[84];                       // tail: issued first,
        float e84t = pt[84];                       // consumed last
        LOADG(Ai0,Ai1,Ai2,At0,At1,At2, 0)
        LOADG(Bi0,Bi1,Bi2,Bt0,Bt1,Bt2, 1)
        LOADG(Ci0,Ci1,Ci2,Ct0,Ct1,Ct2, 2)
        CONSG(Ai0,Ai1,Ai2,At0,At1,At2)             // g0
        LOADG(Ai0,Ai1,Ai2,At0,At1,At2, 3)
        CONSG(Bi0,Bi1,Bi2,Bt0,Bt1,Bt2)             // g1
        LOADG(Bi0,Bi1,Bi2,Bt0,Bt1,Bt2, 4)
        CONSG(Ci0,Ci1,Ci2,Ct0,Ct1,Ct2)             // g2
        LOADG(Ci0,Ci1,Ci2,Ct0,Ct1,Ct2, 5)
        CONSG(Ai0,Ai1,Ai2,At0,At1,At2)             // g3
        LOADG(Ai0,Ai1,Ai2,At0,At1,At2, 6)
        CONSG(Bi0,Bi1,Bi2,Bt0,Bt1,Bt2)             // g4
        CONSG(Ci0,Ci1,Ci2,Ct0,Ct1,Ct2)             // g5
        CONSG(Ai0,Ai1,Ai2,At0,At1,At2)             // g6
        C1(e84i, e84t)                             // elem 84

        float S = l;
        float sumL  = a1 - S;
        float sumL2 = b2 - S * S;
        qrow = fmaf(S, S, -(2.0f / 85.0f) * (S * sumL - sumL2));
#undef LOADG
#undef C1
#undef CONSG
    }

    // ---- Block reduction -> one plain store per block (no atomics) ----
    float val = qrow;
    #pragma unroll
    for (int m = 32; m > 0; m >>= 1)
        val += __shfl_xor(val, m, 64);
    if (lane == 0) wsum[wave] = val;
    __syncthreads();
    if (tid == 0) {
        float s = 0.0f;
        #pragma unroll
        for (int w = 0; w < NWAVES; ++w) s += wsum[w];
        partial[blockIdx.x] = s;
    }
}

// Stage 2: reduce n partials (n = grid), write 0.1 * sum. One block.
__global__ __launch_bounds__(THREADS) void qfd_reduce_kernel(
    const float* __restrict__ partial, float* __restrict__ out, int n) {
    __shared__ float wsum[NWAVES];
    const int tid = threadIdx.x;
    float s = 0.0f;
    for (int i = tid; i < n; i += THREADS) s += partial[i];
    #pragma unroll
    for (int m = 32; m > 0; m >>= 1)
        s += __shfl_xor(s, m, 64);
    if ((tid & 63) == 0) wsum[tid >> 6] = s;
    __syncthreads();
    if (tid == 0) {
        float t = 0.0f;
        #pragma unroll
        for (int w = 0; w < NWAVES; ++w) t += wsum[w];
        out[0] = 0.1f * t;
    }
}

extern "C" void kernel_launch(void* const* d_in, const int* in_sizes, int n_in,
                              void* d_out, int out_size, void* d_ws, size_t ws_size,
                              hipStream_t stream) {
    const float* in  = (const float*)d_in[0];
    const float* tgt = (const float*)d_in[1];
    float* out = (float*)d_out;
    float* partial = (float*)d_ws;               // grid floats (<= 16 KB scratch)

    const int B = in_sizes[0] / QFD_D;           // 262144
    const int grid = (B + THREADS - 1) / THREADS; // 1024 blocks -> 4/CU

    qfd_kernel<<<grid, THREADS, 0, stream>>>(in, tgt, partial, B);
    qfd_reduce_kernel<<<1, THREADS, 0, stream>>>(partial, out, grid);
}

// Round 3
// 204.411 us; speedup vs baseline: 1.0698x; 1.0698x over previous
//
#include <hip/hip_runtime.h>

// QFD loss: out = 0.1 * sum_b diff_b^T A diff_b, A_ij = 1 - |i-j|/85.
// Identity: q = S^2 - (2/85) * (S*sumL - sumL2), where
//   L_k = prefix sums of d, sumL = sum_{k<84} L_k, sumL2 = sum_{k<84} L_k^2.
//
// R8: R7 (register ring) was collapsed by regalloc (VGPR=40 proves the 72-reg
// ring never existed) -> latency-serialized at 2.0 TB/s. Third failure of
// source-level register pipelining; only global_load_lds DMA has sustained
// depth. R5 (66us) had just 3 barrier-coupled drain domains/CU. Fix: 1-wave
// blocks, 16 rows, 12.3 KB LDS -> 13 independent single-shot DMA streams/CU
// (LDS-bound, < 16-workgroup cap). A vmcnt(0) drain now stalls 1/13 of the
// CU instead of 1/3; ~150 KB DMA in flight/CU; drains and compute phases
// mutually cover across 13 decoupled waves.

#define QFD_D 85
#define ROWS_PER_BLOCK 16
#define THREADS 64

// Per block per array: 16*85 = 1360 floats = 340 float4s.
// 6 wave-rounds of 64 = 384 slots (tail 340..383 = clamped junk, never read).
#define F4_VALID 340
#define ROUNDS 6
#define BUF_FLOATS (ROUNDS * 256)   // 1536 floats = 6144 B per array

typedef __attribute__((address_space(1))) const void glob_cv;
typedef __attribute__((address_space(3))) void lds_v;

__global__ __launch_bounds__(THREADS) void qfd_kernel(
    const float* __restrict__ in, const float* __restrict__ tgt,
    float* __restrict__ partial) {
    __shared__ float lin[BUF_FLOATS];   // 6144 B
    __shared__ float ltg[BUF_FLOATS];   // 6144 B  -> 12288 B total
    const int lane = threadIdx.x;       // single wave
    const long base4 = (long)blockIdx.x * F4_VALID;

    const float4* in4 = reinterpret_cast<const float4*>(in) + base4;
    const float4* tg4 = reinterpret_cast<const float4*>(tgt) + base4;

    // ---- Async DMA staging: 12 global_load_lds_dwordx4 (1 KB each), zero
    // dest VGPRs -> all 12 KB in flight; nothing for regalloc to serialize.
    #pragma unroll
    for (int r = 0; r < ROUNDS; ++r) {
        int idx = r * 64 + lane;
        int g = idx < F4_VALID ? idx : 0;      // clamp tail (junk, never read)
        __builtin_amdgcn_global_load_lds(
            (glob_cv*)(in4 + g), (lds_v*)&lin[r * 256], 16, 0, 0);
        __builtin_amdgcn_global_load_lds(
            (glob_cv*)(tg4 + g), (lds_v*)&ltg[r * 256], 16, 0, 0);
    }
    __syncthreads();   // single-wave: just the vmcnt(0) drain we need

    // ---- Segmented per-row scan (verified R5): thread = 4*row + q.
    // Segments: q0=[0,22) len 22, q1=[22,43), q2=[43,64), q3=[64,85) len 21.
    const int q   = lane & 3;
    const int row = lane >> 2;                 // 0..15
    const int off = 21 * q + (q != 0);         // 0,22,43,64
    const int p   = row * QFD_D + off;

    float l = 0.0f, a1 = 0.0f, b2 = 0.0f;
    #pragma unroll
    for (int j = 0; j < 21; ++j) {
        float v = fabsf(lin[p + j] - ltg[p + j]);
        l += v;
        a1 += l;
        b2 = fmaf(l, l, b2);
    }
    if (q == 0) {                              // segment 0 has 22 elements
        float v = fabsf(lin[p + 21] - ltg[p + 21]);
        l += v;
        a1 += l;
        b2 = fmaf(l, l, b2);
    }

    // ---- Quad combine via shuffles. P = exclusive prefix of seg sums.
    const int qb = lane & 60;
    float s0 = __shfl(l, qb + 0, 64);
    float s1 = __shfl(l, qb + 1, 64);
    float s2 = __shfl(l, qb + 2, 64);
    float s3 = __shfl(l, qb + 3, 64);
    float S  = (s0 + s1) + (s2 + s3);
    float P  = (q > 0 ? s0 : 0.0f) + (q > 1 ? s1 : 0.0f) + (q > 2 ? s2 : 0.0f);
    float len = (q == 0) ? 22.0f : 21.0f;
    float c1 = fmaf(len, P, a1);
    float c2 = fmaf(len * P, P, fmaf(2.0f * P, a1, b2));
    float c1s = __shfl(c1, qb + 0, 64) + __shfl(c1, qb + 1, 64)
              + __shfl(c1, qb + 2, 64) + __shfl(c1, qb + 3, 64);
    float c2s = __shfl(c2, qb + 0, 64) + __shfl(c2, qb + 1, 64)
              + __shfl(c2, qb + 2, 64) + __shfl(c2, qb + 3, 64);
    float sumL  = c1s - S;
    float sumL2 = c2s - S * S;
    float qrow  = fmaf(S, S, -(2.0f / 85.0f) * (S * sumL - sumL2));
    float val   = (q == 0) ? qrow : 0.0f;

    // ---- Wave reduction -> one plain store per block (no atomics) ----
    #pragma unroll
    for (int m = 32; m > 0; m >>= 1)
        val += __shfl_xor(val, m, 64);
    if (lane == 0) partial[blockIdx.x] = val;
}

// Stage 2: reduce n partials (n = 16384), write 0.1 * sum. One block.
__global__ __launch_bounds__(256) void qfd_reduce_kernel(
    const float* __restrict__ partial, float* __restrict__ out, int n) {
    __shared__ float wsum[4];
    const int tid = threadIdx.x;
    float s = 0.0f;
    for (int i = tid; i < n; i += 256) s += partial[i];
    #pragma unroll
    for (int m = 32; m > 0; m >>= 1)
        s += __shfl_xor(s, m, 64);
    if ((tid & 63) == 0) wsum[tid >> 6] = s;
    __syncthreads();
    if (tid == 0) {
        float t = 0.0f;
        #pragma unroll
        for (int w = 0; w < 4; ++w) t += wsum[w];
        out[0] = 0.1f * t;
    }
}

extern "C" void kernel_launch(void* const* d_in, const int* in_sizes, int n_in,
                              void* d_out, int out_size, void* d_ws, size_t ws_size,
                              hipStream_t stream) {
    const float* in  = (const float*)d_in[0];
    const float* tgt = (const float*)d_in[1];
    float* out = (float*)d_out;
    float* partial = (float*)d_ws;             // 16384 floats = 64 KB scratch

    const int B = in_sizes[0] / QFD_D;         // 262144
    const int grid = B / ROWS_PER_BLOCK;       // 16384 blocks (1 wave each)

    qfd_kernel<<<grid, THREADS, 0, stream>>>(in, tgt, partial);
    qfd_reduce_kernel<<<1, 256, 0, stream>>>(partial, out, grid);
}

// Round 5
// 199.779 us; speedup vs baseline: 1.0946x; 1.0232x over previous
//
#include <hip/hip_runtime.h>

// QFD loss: out = 0.1 * sum_b diff_b^T A diff_b, A_ij = 1 - |i-j|/85.
// Identity: q = S^2 - (2/85) * (S*sumL - sumL2), where
//   L_k = prefix sums of d, sumL = sum_{k<84} L_k, sumL2 = sum_{k<84} L_k^2.
// Segment semigroup (len,s,a1,b2) with global combine:
//   c1 = len*P + a1, c2 = len*P^2 + 2P*a1 + b2  (P = excl prefix of seg sums)
//   sum over segs: c1s = sumL + S, c2s = sumL2 + S^2.
//
// R10: R9's 16.3% error was a divergent-__shfl bug: lo1/lo2 shfl sat inside
// the (rr==0) ternary, so row-1 lanes read lane 20 while lane 20 was
// exec-masked off -> ds_bpermute from inactive lane = undefined. Algebra
// verified exact on closed-form row (d=1: c1s=3655, c2s=208335, q=4817).
// Fix: unconditional shfl with clamped source lane + post-select. Rest
// identical to R9: plain coalesced loads, no LDS data path, no barriers,
// TLP-only latency hiding; 3 rows/wave, lane = 21r+c owns 4 floats,
// c==20 lanes add the row tail (len-5 segment) via exec-masked scalars.

#define QFD_D 85
#define THREADS 256
#define NWAVES (THREADS / 64)

// 4-byte-aligned float4 (group stride 255 floats breaks 16B alignment).
typedef float f4a __attribute__((ext_vector_type(4), aligned(4)));

__global__ __launch_bounds__(THREADS, 6) void qfd_kernel(
    const float* __restrict__ in, const float* __restrict__ tgt,
    float* __restrict__ partial, int B, int ngroups) {
    __shared__ float wsum[NWAVES];
    const int tid  = threadIdx.x;
    const int lane = tid & 63;
    const int wave = tid >> 6;

    // lane -> (row-in-group r, segment c). Lane 63 is a dead lane (r=3).
    const int r = (lane < 21) ? 0 : (lane < 42) ? 1 : (lane < 63) ? 2 : 3;
    const int c = lane - 21 * r;            // 0..20
    const bool isC20 = (c == 20) && (r < 3);
    const int limv = B * QFD_D - 4;         // clamp for f4 loads
    const int lims = B * QFD_D - 1;         // clamp for scalar loads

    const int wid     = blockIdx.x * NWAVES + wave;
    const int wstride = gridDim.x * NWAVES;

    float acc = 0.0f;

    for (int g = wid; g < ngroups; g += wstride) {
        const int base = g * 255;
        const int row  = 3 * g + r;
        const bool valid = (r < 3) && (row < B);

        int off = base + r * 85 + c * 4;
        off = off > limv ? limv : off;
        f4a vi = *(const f4a*)(in  + off);
        f4a vt = *(const f4a*)(tgt + off);

        // row tail (element 84): 3 active lanes, exec-masked
        float ti = 0.0f, tt = 0.0f;
        if (isC20) {
            int toff = base + r * 85 + 84;
            toff = toff > lims ? lims : toff;
            ti = in[toff];
            tt = tgt[toff];
        }

        float d0 = valid ? fabsf(vi.x - vt.x) : 0.0f;
        float d1 = valid ? fabsf(vi.y - vt.y) : 0.0f;
        float d2 = valid ? fabsf(vi.z - vt.z) : 0.0f;
        float d3 = valid ? fabsf(vi.w - vt.w) : 0.0f;

        // in-register scan of the 4(+1)-element segment
        float l  = d0;
        float a1 = l;
        float b2 = l * l;
        l += d1; a1 += l; b2 = fmaf(l, l, b2);
        l += d2; a1 += l; b2 = fmaf(l, l, b2);
        l += d3; a1 += l; b2 = fmaf(l, l, b2);
        const bool ct = isC20 && valid;
        float d4 = ct ? fabsf(ti - tt) : 0.0f;
        float l5 = l + d4;
        a1 += ct ? l5 : 0.0f;
        b2 = ct ? fmaf(l5, l5, b2) : b2;
        l  = ct ? l5 : l;
        float s = l;

        // wave-inclusive prefix of segment sums (shfl unconditional; only
        // the add is guarded -> all source lanes always active)
        float ps = s;
        #pragma unroll
        for (int d = 1; d < 64; d <<= 1) {
            float t = __shfl_up(ps, d, 64);
            if (lane >= d) ps += t;
        }
        float bs1 = __shfl(ps, 20, 64);   // row0 total
        float bs2 = __shfl(ps, 41, 64);   // rows0+1 total
        float rowbase = (r == 0) ? 0.0f : (r == 1) ? bs1 : bs2;
        float P = ps - s - rowbase;       // exclusive prefix within row
        float len = ct ? 5.0f : 4.0f;
        float c1 = fmaf(len, P, a1);
        float c2 = fmaf(len * P, P, fmaf(2.0f * P, a1, b2));

        // prefix scans of c1, c2 for per-row boundary differences
        float pc1 = c1, pc2 = c2;
        #pragma unroll
        for (int d = 1; d < 64; d <<= 1) {
            float t1 = __shfl_up(pc1, d, 64);
            float t2 = __shfl_up(pc2, d, 64);
            if (lane >= d) { pc1 += t1; pc2 += t2; }
        }

        // per-row totals. ALL shfls unconditional (R9 bug fix): clamp the
        // source lane and select after, so no read from an inactive lane.
        int rr = (r < 3) ? r : 2;
        int e  = 21 * rr + 20;
        float S   = __shfl(ps, e, 64) - ((rr == 0) ? 0.0f : (rr == 1) ? bs1 : bs2);
        float hi1 = __shfl(pc1, e, 64);
        float hi2 = __shfl(pc2, e, 64);
        int lo_lane = (rr == 0) ? 0 : (21 * rr - 1);
        float lo1 = __shfl(pc1, lo_lane, 64);
        float lo2 = __shfl(pc2, lo_lane, 64);
        lo1 = (rr == 0) ? 0.0f : lo1;
        lo2 = (rr == 0) ? 0.0f : lo2;
        float c1s = hi1 - lo1;
        float c2s = hi2 - lo2;
        float sumL  = c1s - S;
        float sumL2 = c2s - S * S;
        float q = fmaf(S, S, -(2.0f / 85.0f) * (S * sumL - sumL2));
        acc += (c == 0 && r < 3) ? q : 0.0f;
    }

    // ---- Block reduction -> one plain store per block ----
    #pragma unroll
    for (int m = 32; m > 0; m >>= 1)
        acc += __shfl_xor(acc, m, 64);
    if (lane == 0) wsum[wave] = acc;
    __syncthreads();
    if (tid == 0) {
        float ssum = 0.0f;
        #pragma unroll
        for (int w = 0; w < NWAVES; ++w) ssum += wsum[w];
        partial[blockIdx.x] = ssum;
    }
}

// Stage 2: reduce n partials, write 0.1 * sum. One block.
__global__ __launch_bounds__(256) void qfd_reduce_kernel(
    const float* __restrict__ partial, float* __restrict__ out, int n) {
    __shared__ float wsum[4];
    const int tid = threadIdx.x;
    float s = 0.0f;
    for (int i = tid; i < n; i += 256) s += partial[i];
    #pragma unroll
    for (int m = 32; m > 0; m >>= 1)
        s += __shfl_xor(s, m, 64);
    if ((tid & 63) == 0) wsum[tid >> 6] = s;
    __syncthreads();
    if (tid == 0) {
        float t = 0.0f;
        #pragma unroll
        for (int w = 0; w < 4; ++w) t += wsum[w];
        out[0] = 0.1f * t;
    }
}

extern "C" void kernel_launch(void* const* d_in, const int* in_sizes, int n_in,
                              void* d_out, int out_size, void* d_ws, size_t ws_size,
                              hipStream_t stream) {
    const float* in  = (const float*)d_in[0];
    const float* tgt = (const float*)d_in[1];
    float* out = (float*)d_out;
    float* partial = (float*)d_ws;            // grid floats (8 KB scratch)

    const int B = in_sizes[0] / QFD_D;        // 262144
    const int ngroups = (B + 2) / 3;          // 87382 (last group: 1 row)
    const int grid = 2048;                    // persistent, 8 blocks/CU

    qfd_kernel<<<grid, THREADS, 0, stream>>>(in, tgt, partial, B, ngroups);
    qfd_reduce_kernel<<<1, 256, 0, stream>>>(partial, out, grid);
}

// Round 6
// 193.706 us; speedup vs baseline: 1.1290x; 1.0313x over previous
//
#include <hip/hip_runtime.h>
#include <hip/hip_bf16.h>

// QFD loss: out = 0.1 * sum_b diff_b^T A diff_b, A_ij = 1 - |i-j|/85.
// Identity: q = S^2 - (2/85) * (S*sumL - sumL2), where
//   L_k = prefix sums of d, sumL = sum_{k<84} L_k, sumL2 = sum_{k<84} L_k^2.
//
// R11 (final): revert to the best-measured structure (R5: 192.7 us harness,
// 66.1 us dispatch). Session evidence (R5-R10): per-CU app-read rate pins at
// ~4.4 B/cy/CU across global_load_lds DMA (3 structures), coalesced VGPR
// loads, and register-ring attempts; L3-warm dispatches run identical times
// (latency x outstanding-lines limited, not BW); tuned LN/RMSNorm kernels
// (82-86% "of achievable BW") sustain the same 4.2-4.4 B/cy/CU read rate.
// 178.3 MB mandatory reads / 2.7 TB/s empirical read ceiling = 66 us: this
// kernel is AT the roofline. No HIP-expressible lever moved the cap.

#define QFD_D 85
#define ROWS_PER_BLOCK 64
#define THREADS 256

// Per block: 64 rows * 85 = 5440 floats = 1360 float4s per input array.
// 22 wave-rounds of 64 float4s = 1408 slots (tail 1360..1407 = clamped junk).
#define F4_VALID 1360
#define ROUNDS 22

typedef __attribute__((address_space(1))) const void glob_cv;
typedef __attribute__((address_space(3))) void lds_v;

__global__ __launch_bounds__(THREADS) void qfd_kernel(
    const float* __restrict__ in, const float* __restrict__ tgt,
    float* __restrict__ partial) {
    __shared__ float lin[ROUNDS * 256];   // 5632 floats = 22528 B
    __shared__ float ltg[ROUNDS * 256];
    __shared__ float wsum[THREADS / 64];

    const int tid  = threadIdx.x;
    const int lane = tid & 63;
    const int wave = tid >> 6;
    const int base4 = blockIdx.x * F4_VALID;   // float4 index; max ~5.57M

    const float4* in4 = reinterpret_cast<const float4*>(in) + base4;
    const float4* tg4 = reinterpret_cast<const float4*>(tgt) + base4;

    // ---- Async DMA staging: each wave issues ~11 global_load_lds_dwordx4
    // (zero dest VGPRs -> all in flight; ~22 KB outstanding per wave).
    // LDS dest per call = wave-uniform base + lane*16. ----
    for (int r = wave; r < ROUNDS; r += 4) {
        int idx = r * 64 + lane;
        int g = idx < F4_VALID ? idx : 0;      // clamp tail (junk, never read)
        __builtin_amdgcn_global_load_lds(
            (glob_cv*)(in4 + g), (lds_v*)&lin[r * 256], 16, 0, 0);
        __builtin_amdgcn_global_load_lds(
            (glob_cv*)(tg4 + g), (lds_v*)&ltg[r * 256], 16, 0, 0);
    }
    __syncthreads();   // compiler emits vmcnt(0) drain before barrier

    // ---- Segmented per-row scan: thread = 4*row + q, segment q of row.
    // Segments: q0=[0,22) len 22, q1=[22,43), q2=[43,64), q3=[64,85) len 21.
    // diff computed on the fly from the two staged arrays. ----
    const int q   = tid & 3;
    const int row = tid >> 2;                  // 0..63
    const int off = 21 * q + (q != 0);         // 0,22,43,64
    const int p   = row * QFD_D + off;

    float l = 0.0f, a1 = 0.0f, b2 = 0.0f;
    #pragma unroll
    for (int j = 0; j < 21; ++j) {
        float v = fabsf(lin[p + j] - ltg[p + j]);
        l += v;
        a1 += l;
        b2 = fmaf(l, l, b2);
    }
    if (q == 0) {                              // segment 0 has 22 elements
        float v = fabsf(lin[p + 21] - ltg[p + 21]);
        l += v;
        a1 += l;
        b2 = fmaf(l, l, b2);
    }

    // ---- Quad combine via shuffles. P = exclusive prefix of seg sums.
    // sumL' = sum_q len_q*P_q + a_q ; sumL2' = sum_q len_q*P_q^2+2P_q a_q+b_q
    // sumL = sumL' - S ; sumL2 = sumL2' - S^2 (drop the L_84 terms). ----
    const int qb = lane & 60;
    float s0 = __shfl(l, qb + 0, 64);
    float s1 = __shfl(l, qb + 1, 64);
    float s2 = __shfl(l, qb + 2, 64);
    float s3 = __shfl(l, qb + 3, 64);
    float S  = (s0 + s1) + (s2 + s3);
    float P  = (q > 0 ? s0 : 0.0f) + (q > 1 ? s1 : 0.0f) + (q > 2 ? s2 : 0.0f);
    float len = (q == 0) ? 22.0f : 21.0f;
    float c1 = fmaf(len, P, a1);
    float c2 = fmaf(len * P, P, fmaf(2.0f * P, a1, b2));
    float c1s = __shfl(c1, qb + 0, 64) + __shfl(c1, qb + 1, 64)
              + __shfl(c1, qb + 2, 64) + __shfl(c1, qb + 3, 64);
    float c2s = __shfl(c2, qb + 0, 64) + __shfl(c2, qb + 1, 64)
              + __shfl(c2, qb + 2, 64) + __shfl(c2, qb + 3, 64);
    float sumL  = c1s - S;
    float sumL2 = c2s - S * S;
    float qrow  = fmaf(S, S, -(2.0f / 85.0f) * (S * sumL - sumL2));
    float val   = (q == 0) ? qrow : 0.0f;

    // ---- Block reduction -> one plain store per block (no atomics) ----
    #pragma unroll
    for (int m = 32; m > 0; m >>= 1)
        val += __shfl_xor(val, m, 64);
    if (lane == 0) wsum[wave] = val;
    __syncthreads();
    if (tid == 0) {
        float s = 0.0f;
        #pragma unroll
        for (int w = 0; w < THREADS / 64; ++w) s += wsum[w];
        partial[blockIdx.x] = s;
    }
}

// Stage 2: reduce n partials (n = 4096), write 0.1 * sum. One block.
__global__ __launch_bounds__(THREADS) void qfd_reduce_kernel(
    const float* __restrict__ partial, float* __restrict__ out, int n) {
    __shared__ float wsum[THREADS / 64];
    const int tid = threadIdx.x;
    float s = 0.0f;
    for (int i = tid; i < n; i += THREADS) s += partial[i];
    #pragma unroll
    for (int m = 32; m > 0; m >>= 1)
        s += __shfl_xor(s, m, 64);
    if ((tid & 63) == 0) wsum[tid >> 6] = s;
    __syncthreads();
    if (tid == 0) {
        float t = 0.0f;
        #pragma unroll
        for (int w = 0; w < THREADS / 64; ++w) t += wsum[w];
        out[0] = 0.1f * t;
    }
}

extern "C" void kernel_launch(void* const* d_in, const int* in_sizes, int n_in,
                              void* d_out, int out_size, void* d_ws, size_t ws_size,
                              hipStream_t stream) {
    const float* in  = (const float*)d_in[0];
    const float* tgt = (const float*)d_in[1];
    float* out = (float*)d_out;
    float* partial = (float*)d_ws;             // 4096 floats = 16 KB scratch

    const int B = in_sizes[0] / QFD_D;         // 262144
    const int grid = B / ROWS_PER_BLOCK;       // 4096 blocks

    qfd_kernel<<<grid, THREADS, 0, stream>>>(in, tgt, partial);
    qfd_reduce_kernel<<<1, THREADS, 0, stream>>>(partial, out, grid);
}